// Round 1
// 998.424 us; speedup vs baseline: 1.0235x; 1.0235x over previous
//
#include <hip/hip_runtime.h>

// Problem constants (fixed by setup_inputs): N = 256*64*64 rows, C = 64.
#define NROWS   1048576
#define SBLK    4096          // spatial positions per block (64*64)

using bfrag = __attribute__((ext_vector_type(8))) short;   // 8 bf16 (4 VGPRs)
using ffrag = __attribute__((ext_vector_type(4))) float;   // 4 fp32 acc
using uifrag = __attribute__((ext_vector_type(4))) unsigned;

__device__ __forceinline__ float bf2f(unsigned short u) {
    unsigned w = ((unsigned)u) << 16;
    return __builtin_bit_cast(float, w);
}
__device__ __forceinline__ unsigned short f2bf(float f) {
    unsigned u = __builtin_bit_cast(unsigned, f);
    u += 0x7fffu + ((u >> 16) & 1u);   // RNE
    return (unsigned short)(u >> 16);
}
__device__ __forceinline__ short pk(float f) { return (short)f2bf(f); }
// packed f32x2 -> bf16x2, RNE (same rounding as f2bf). No builtin on gfx950.
__device__ __forceinline__ unsigned cvtpk(float lo, float hi) {
    unsigned r;
    asm("v_cvt_pk_bf16_f32 %0, %1, %2" : "=v"(r) : "v"(lo), "v"(hi));
    return r;
}

// ---------------------------------------------------------------------------
// K0: cast weights to bf16 in B^T[n][k] fragment-friendly layout.
//  layer convs: W given (o,c), need BT[o][c] -> as-is, just cast.
//  uW1 given (c=0..127, o): uW1bt[o*128+c] = uW1[c*64+o]
//  uW2 given (c, o):        uW2bt[o*64+c]  = uW2[c*64+o]
// ---------------------------------------------------------------------------
__global__ void k_prep(const float* __restrict__ w11, const float* __restrict__ w12,
                       const float* __restrict__ w21, const float* __restrict__ w22,
                       const float* __restrict__ uW1, const float* __restrict__ uW2,
                       unsigned short* __restrict__ w11b, unsigned short* __restrict__ w12b,
                       unsigned short* __restrict__ w21b, unsigned short* __restrict__ w22b,
                       unsigned short* __restrict__ uW1bt, unsigned short* __restrict__ uW2bt)
{
    int t = threadIdx.x;
    for (int i = t; i < 4096; i += 256) {
        w11b[i] = f2bf(w11[i]);
        w12b[i] = f2bf(w12[i]);
        w21b[i] = f2bf(w21[i]);
        w22b[i] = f2bf(w22[i]);
        int o = i >> 6, c = i & 63;
        uW2bt[o * 64 + c] = f2bf(uW2[c * 64 + o]);
    }
    for (int i = t; i < 8192; i += 256) {
        int o = i >> 7, c = i & 127;
        uW1bt[o * 128 + c] = f2bf(uW1[c * 64 + o]);
    }
}

// ---------------------------------------------------------------------------
// K1: both 2-layer MLP branches via operand-SWAPPED MFMA: D = W · X^T = Z^T.
// Barrier-free: each wave owns one 64-row tile end to end.
//  - W frag = row-major (o,c) weights, identical addressing as before.
//  - X frag = direct global fp32 loads + cvt_pk (no LDS stage).
//  - D lanes hold 4 consecutive output channels of one spatial row:
//      layer1 -> ts[s][c] via single ds_write_b64 per ot  (2x cvt_pk)
//      layer2 -> store straight to M[b][o][s]  (no transpose buffer)
// ---------------------------------------------------------------------------
__global__ __launch_bounds__(256, 3) void k_mlp(
    const float* __restrict__ x,
    const unsigned short* __restrict__ w11b, const float* __restrict__ b11,
    const unsigned short* __restrict__ w12b, const float* __restrict__ b12,
    const unsigned short* __restrict__ w21b, const float* __restrict__ b21,
    const unsigned short* __restrict__ w22b, const float* __restrict__ b22,
    unsigned short* __restrict__ M1, unsigned short* __restrict__ M2)
{
    __shared__ unsigned short ts[4][64 * 72];   // per-wave Z1 (64 s x 64 c, pad 72)
    const int t   = threadIdx.x;
    const int w   = t >> 6, ln = t & 63;
    const int col = ln & 15, q = ln >> 4;
    unsigned short* tsw = ts[w];

    const int nw = gridDim.x * 4;
    for (int tile = blockIdx.x * 4 + w; tile < NROWS / 64; tile += nw) {
        const int n0 = tile * 64;
        const int b = n0 >> 12, s0 = n0 & (SBLK - 1);

        // x fragments for the 4 m-tiles (B-operand role; same lane layout as A)
        bfrag ax[4][2];
        #pragma unroll
        for (int mt = 0; mt < 4; ++mt) {
            const float* xr = x + (size_t)(n0 + mt * 16 + col) * 64 + q * 8;
            #pragma unroll
            for (int kt = 0; kt < 2; ++kt) {
                float4 lo = *reinterpret_cast<const float4*>(xr + kt * 32);
                float4 hi = *reinterpret_cast<const float4*>(xr + kt * 32 + 4);
                uifrag u;
                u[0] = cvtpk(lo.x, lo.y);
                u[1] = cvtpk(lo.z, lo.w);
                u[2] = cvtpk(hi.x, hi.y);
                u[3] = cvtpk(hi.z, hi.w);
                ax[mt][kt] = __builtin_bit_cast(bfrag, u);
            }
        }

        #pragma unroll
        for (int br = 0; br < 2; ++br) {
            const unsigned short* wA = br ? w21b : w11b;
            const unsigned short* wB = br ? w22b : w12b;
            const float* bA = br ? b21 : b11;
            const float* bB = br ? b22 : b12;
            unsigned short* Mb = (br ? M2 : M1) + ((size_t)b << 18) + s0;

            // ---- layer 1: Z1^T = relu(W1 . X^T + b) ----
            bfrag  bw[4][2];
            float4 bsv[4];
            #pragma unroll
            for (int ot = 0; ot < 4; ++ot) {
                #pragma unroll
                for (int kt = 0; kt < 2; ++kt)
                    bw[ot][kt] = *reinterpret_cast<const bfrag*>(
                        wA + (ot * 16 + col) * 64 + kt * 32 + q * 8);
                bsv[ot] = *reinterpret_cast<const float4*>(bA + ot * 16 + q * 4);
            }
            #pragma unroll
            for (int mt = 0; mt < 4; ++mt) {
                #pragma unroll
                for (int ot = 0; ot < 4; ++ot) {
                    ffrag acc = {0.f, 0.f, 0.f, 0.f};
                    acc = __builtin_amdgcn_mfma_f32_16x16x32_bf16(bw[ot][0], ax[mt][0], acc, 0, 0, 0);
                    acc = __builtin_amdgcn_mfma_f32_16x16x32_bf16(bw[ot][1], ax[mt][1], acc, 0, 0, 0);
                    float4 bs = bsv[ot];
                    unsigned u0 = cvtpk(fmaxf(acc[0] + bs.x, 0.f), fmaxf(acc[1] + bs.y, 0.f));
                    unsigned u1 = cvtpk(fmaxf(acc[2] + bs.z, 0.f), fmaxf(acc[3] + bs.w, 0.f));
                    // lane holds channels ot*16+q*4 .. +3 of spatial row mt*16+col
                    *reinterpret_cast<uint2*>(&tsw[(mt * 16 + col) * 72 + ot * 16 + q * 4]) =
                        make_uint2(u0, u1);
                }
            }
            // ---- layer 2: Z2^T = relu(W2 . Z1^T + b); store direct to M[b][o][s] ----
            #pragma unroll
            for (int ot = 0; ot < 4; ++ot) {
                #pragma unroll
                for (int kt = 0; kt < 2; ++kt)
                    bw[ot][kt] = *reinterpret_cast<const bfrag*>(
                        wB + (ot * 16 + col) * 64 + kt * 32 + q * 8);
                bsv[ot] = *reinterpret_cast<const float4*>(bB + ot * 16 + q * 4);
            }
            #pragma unroll
            for (int mt = 0; mt < 4; ++mt) {
                // same-wave ts readback; in-order DS pipe, no barrier needed
                bfrag az0 = *reinterpret_cast<const bfrag*>(&tsw[(mt * 16 + col) * 72 + q * 8]);
                bfrag az1 = *reinterpret_cast<const bfrag*>(&tsw[(mt * 16 + col) * 72 + 32 + q * 8]);
                #pragma unroll
                for (int ot = 0; ot < 4; ++ot) {
                    ffrag acc = {0.f, 0.f, 0.f, 0.f};
                    acc = __builtin_amdgcn_mfma_f32_16x16x32_bf16(bw[ot][0], az0, acc, 0, 0, 0);
                    acc = __builtin_amdgcn_mfma_f32_16x16x32_bf16(bw[ot][1], az1, acc, 0, 0, 0);
                    float4 bs = bsv[ot];
                    unsigned u0 = cvtpk(fmaxf(acc[0] + bs.x, 0.f), fmaxf(acc[1] + bs.y, 0.f));
                    unsigned u1 = cvtpk(fmaxf(acc[2] + bs.z, 0.f), fmaxf(acc[3] + bs.w, 0.f));
                    unsigned short* mp = Mb + (size_t)(ot * 16 + q * 4) * SBLK + mt * 16 + col;
                    mp[0]        = (unsigned short)u0;
                    mp[SBLK]     = (unsigned short)(u0 >> 16);
                    mp[2 * SBLK] = (unsigned short)u1;
                    mp[3 * SBLK] = (unsigned short)(u1 >> 16);
                }
            }
        }
    }
}

// ---------------------------------------------------------------------------
// K2: corr[b,c] = A(64x64) @ B(64x64);  h = sqrt(relu(corr)) IN-PLACE over M1.
// MFMA version: one WG = 4 (b,c) chunks. Cooperative LDS transpose of B
// (Bt[j][k]) -> B-frag b128 reads; A-frag direct global b128 (already bf16).
// Wave w owns m-tile i = w*16.. of all 4 chunks (reads/writes its own rows
// only -> in-place safe).
// ---------------------------------------------------------------------------
__global__ __launch_bounds__(256, 4) void k_corr(
    unsigned short* __restrict__ M1, const unsigned short* __restrict__ M2)
{
    __shared__ unsigned short Bt[4][64 * 72];
    const int t   = threadIdx.x;
    const int w   = t >> 6, ln = t & 63;
    const int col = ln & 15, q = ln >> 4;
    const size_t cb = (size_t)blockIdx.x << 14;   // 4 chunks of 4096

    // stage B^T: thread t covers row k = t>>2, cols j0..j0+15
    const int k = t >> 2, j0 = (t & 3) * 16;
    #pragma unroll
    for (int cc = 0; cc < 4; ++cc) {
        const unsigned short* Bc = M2 + cb + cc * 4096 + (size_t)k * 64 + j0;
        uint4 p0 = reinterpret_cast<const uint4*>(Bc)[0];
        uint4 p1 = reinterpret_cast<const uint4*>(Bc)[1];
        unsigned pv[8] = { p0.x, p0.y, p0.z, p0.w, p1.x, p1.y, p1.z, p1.w };
        #pragma unroll
        for (int m = 0; m < 8; ++m) {
            Bt[cc][(j0 + 2 * m) * 72 + k]     = (unsigned short)(pv[m] & 0xffff);
            Bt[cc][(j0 + 2 * m + 1) * 72 + k] = (unsigned short)(pv[m] >> 16);
        }
    }
    __syncthreads();

    #pragma unroll
    for (int cc = 0; cc < 4; ++cc) {
        unsigned short* Ac = M1 + cb + cc * 4096;
        bfrag a0 = *reinterpret_cast<const bfrag*>(Ac + (w * 16 + col) * 64 + q * 8);
        bfrag a1 = *reinterpret_cast<const bfrag*>(Ac + (w * 16 + col) * 64 + 32 + q * 8);
        #pragma unroll
        for (int nj = 0; nj < 4; ++nj) {
            bfrag bq0 = *reinterpret_cast<const bfrag*>(&Bt[cc][(nj * 16 + col) * 72 + q * 8]);
            bfrag bq1 = *reinterpret_cast<const bfrag*>(&Bt[cc][(nj * 16 + col) * 72 + 32 + q * 8]);
            ffrag acc = {0.f, 0.f, 0.f, 0.f};
            acc = __builtin_amdgcn_mfma_f32_16x16x32_bf16(a0, bq0, acc, 0, 0, 0);
            acc = __builtin_amdgcn_mfma_f32_16x16x32_bf16(a1, bq1, acc, 0, 0, 0);
            unsigned u0 = cvtpk(sqrtf(fmaxf(acc[0], 0.f)), sqrtf(fmaxf(acc[1], 0.f)));
            unsigned u1 = cvtpk(sqrtf(fmaxf(acc[2], 0.f)), sqrtf(fmaxf(acc[3], 0.f)));
            unsigned short* hp = Ac + (size_t)(w * 16 + q * 4) * 64 + nj * 16 + col;
            hp[0]   = (unsigned short)u0;
            hp[64]  = (unsigned short)(u0 >> 16);
            hp[128] = (unsigned short)u1;
            hp[192] = (unsigned short)(u1 >> 16);
        }
    }
}

// ---------------------------------------------------------------------------
// K3: z1 = [x, h] @ uW1 + ub1 via MFMA (K=128), BN1 stats fused.
// x-part A-frags straight from fp32 global; h-part via WAVE-PRIVATE LDS
// transpose of H (lane = channel, 16 s-rows per wave) -> no in-loop barriers.
// ---------------------------------------------------------------------------
__global__ __launch_bounds__(256) void k_fc1(
    const float* __restrict__ x, const unsigned short* __restrict__ H,
    const unsigned short* __restrict__ uW1bt, const float* __restrict__ ub1,
    unsigned short* __restrict__ Z1, float* __restrict__ sum1, float* __restrict__ sq1)
{
    __shared__ unsigned short hs[4][16 * 72];
    __shared__ float redS[4][64], redQ[4][64];
    const int t   = threadIdx.x;
    const int w   = t >> 6, ln = t & 63;
    const int col = ln & 15, q = ln >> 4;
    unsigned short* hsw = hs[w];

    // resident B-frags (16 x 4 VGPRs) + bias
    bfrag bw[4][4];
    #pragma unroll
    for (int kt = 0; kt < 4; ++kt)
        #pragma unroll
        for (int ct = 0; ct < 4; ++ct)
            bw[kt][ct] = *reinterpret_cast<const bfrag*>(
                uW1bt + (ct * 16 + col) * 128 + kt * 32 + q * 8);
    float bias[4];
    #pragma unroll
    for (int ct = 0; ct < 4; ++ct) bias[ct] = ub1[ct * 16 + col];

    float sA[4] = {0, 0, 0, 0}, qA[4] = {0, 0, 0, 0};

    for (int blk = blockIdx.x; blk < NROWS / 64; blk += gridDim.x) {
        const int n0 = blk * 64;
        const int b = n0 >> 12, s0 = n0 & (SBLK - 1);

        // wave-private H^T stage: lane ln = channel, this wave's 16 s rows
        {
            const unsigned short* hp = H + ((size_t)b << 18) + (size_t)ln * SBLK + s0 + w * 16;
            uint4 p0 = reinterpret_cast<const uint4*>(hp)[0];
            uint4 p1 = reinterpret_cast<const uint4*>(hp)[1];
            unsigned pv[8] = { p0.x, p0.y, p0.z, p0.w, p1.x, p1.y, p1.z, p1.w };
            #pragma unroll
            for (int m = 0; m < 8; ++m) {
                hsw[(2 * m + 0) * 72 + ln] = (unsigned short)(pv[m] & 0xffff);
                hsw[(2 * m + 1) * 72 + ln] = (unsigned short)(pv[m] >> 16);
            }
        }

        const int row = w * 16 + col;
        bfrag ax[2];
        #pragma unroll
        for (int kt = 0; kt < 2; ++kt) {
            const float* xp = x + (size_t)(n0 + row) * 64 + kt * 32 + q * 8;
            float4 lo = reinterpret_cast<const float4*>(xp)[0];
            float4 hi = reinterpret_cast<const float4*>(xp)[1];
            uifrag u;
            u[0] = cvtpk(lo.x, lo.y);
            u[1] = cvtpk(lo.z, lo.w);
            u[2] = cvtpk(hi.x, hi.y);
            u[3] = cvtpk(hi.z, hi.w);
            ax[kt] = __builtin_bit_cast(bfrag, u);
        }
        // same-wave readback, in-order DS pipe -> no barrier
        bfrag ah0 = *reinterpret_cast<const bfrag*>(&hsw[col * 72 + q * 8]);
        bfrag ah1 = *reinterpret_cast<const bfrag*>(&hsw[col * 72 + 32 + q * 8]);

        #pragma unroll
        for (int ct = 0; ct < 4; ++ct) {
            ffrag acc = {0.f, 0.f, 0.f, 0.f};
            acc = __builtin_amdgcn_mfma_f32_16x16x32_bf16(ax[0], bw[0][ct], acc, 0, 0, 0);
            acc = __builtin_amdgcn_mfma_f32_16x16x32_bf16(ax[1], bw[1][ct], acc, 0, 0, 0);
            acc = __builtin_amdgcn_mfma_f32_16x16x32_bf16(ah0,  bw[2][ct], acc, 0, 0, 0);
            acc = __builtin_amdgcn_mfma_f32_16x16x32_bf16(ah1,  bw[3][ct], acc, 0, 0, 0);
            #pragma unroll
            for (int r = 0; r < 4; ++r) {
                float v = acc[r] + bias[ct];
                Z1[(size_t)(n0 + w * 16 + q * 4 + r) * 64 + ct * 16 + col] = f2bf(v);
                sA[ct] += v; qA[ct] += v * v;
            }
        }
    }

    // fused BN stats: quad-shfl reduce -> LDS -> one atomic per channel per WG
    #pragma unroll
    for (int ct = 0; ct < 4; ++ct) {
        float s = sA[ct], qq = qA[ct];
        s  += __shfl_xor(s, 16);  s  += __shfl_xor(s, 32);
        qq += __shfl_xor(qq, 16); qq += __shfl_xor(qq, 32);
        if (q == 0) { redS[w][ct * 16 + col] = s; redQ[w][ct * 16 + col] = qq; }
    }
    __syncthreads();
    if (t < 64) {
        float S = redS[0][t] + redS[1][t] + redS[2][t] + redS[3][t];
        float Q = redQ[0][t] + redQ[1][t] + redQ[2][t] + redQ[3][t];
        atomicAdd(&sum1[t], S);
        atomicAdd(&sq1[t], Q);
    }
}

__global__ void k_final(const float* __restrict__ sum, const float* __restrict__ sq,
                        const float* __restrict__ g, const float* __restrict__ be,
                        float* __restrict__ scale, float* __restrict__ shift)
{
    int c = threadIdx.x;
    if (c < 64) {
        const float invN = 1.f / (float)NROWS;
        float mu  = sum[c] * invN;
        float var = sq[c] * invN - mu * mu;
        float rs  = rsqrtf(var + 1e-5f);
        float sc  = g[c] * rs;
        scale[c] = sc;
        shift[c] = be[c] - mu * sc;
    }
}

// ---------------------------------------------------------------------------
// K5: y = relu(BN1(z1)); z2 = y @ uW2 + ub2 via MFMA, BN2 stats fused.
// Fully LDS-free main loop: A direct from global w/ BN applied in regs.
// ---------------------------------------------------------------------------
__global__ __launch_bounds__(256) void k_fc2(
    const unsigned short* __restrict__ Z1, const unsigned short* __restrict__ uW2bt,
    const float* __restrict__ ub2, const float* __restrict__ scale1,
    const float* __restrict__ shift1,
    unsigned short* __restrict__ Z2, float* __restrict__ sum2, float* __restrict__ sq2)
{
    __shared__ float redS[4][64], redQ[4][64];
    const int t   = threadIdx.x;
    const int w   = t >> 6, ln = t & 63;
    const int col = ln & 15, q = ln >> 4;

    bfrag bw[2][4];
    #pragma unroll
    for (int kt = 0; kt < 2; ++kt)
        #pragma unroll
        for (int ct = 0; ct < 4; ++ct)
            bw[kt][ct] = *reinterpret_cast<const bfrag*>(
                uW2bt + (ct * 16 + col) * 64 + kt * 32 + q * 8);
    float bias[4];
    #pragma unroll
    for (int ct = 0; ct < 4; ++ct) bias[ct] = ub2[ct * 16 + col];
    float sc[2][8], sh[2][8];
    #pragma unroll
    for (int kt = 0; kt < 2; ++kt)
        #pragma unroll
        for (int j = 0; j < 8; ++j) {
            int c = kt * 32 + q * 8 + j;
            sc[kt][j] = scale1[c];
            sh[kt][j] = shift1[c];
        }

    float sA[4] = {0, 0, 0, 0}, qA[4] = {0, 0, 0, 0};

    const int wg = blockIdx.x * 4 + w;
    const int stride = gridDim.x * 4;
    for (int tile = wg; tile < NROWS / 16; tile += stride) {
        const size_t rbase = (size_t)tile * 16;
        bfrag a[2];
        #pragma unroll
        for (int kt = 0; kt < 2; ++kt) {
            const unsigned short* zp = Z1 + (rbase + col) * 64 + kt * 32 + q * 8;
            uint4 p = *reinterpret_cast<const uint4*>(zp);
            unsigned pv[4] = { p.x, p.y, p.z, p.w };
            bfrag av;
            #pragma unroll
            for (int m = 0; m < 4; ++m) {
                float lo = bf2f((unsigned short)(pv[m] & 0xffff));
                float hi = bf2f((unsigned short)(pv[m] >> 16));
                lo = fmaxf(fmaf(lo, sc[kt][2 * m],     sh[kt][2 * m]),     0.f);
                hi = fmaxf(fmaf(hi, sc[kt][2 * m + 1], sh[kt][2 * m + 1]), 0.f);
                av[2 * m] = pk(lo); av[2 * m + 1] = pk(hi);
            }
            a[kt] = av;
        }
        #pragma unroll
        for (int ct = 0; ct < 4; ++ct) {
            ffrag acc = {0.f, 0.f, 0.f, 0.f};
            acc = __builtin_amdgcn_mfma_f32_16x16x32_bf16(a[0], bw[0][ct], acc, 0, 0, 0);
            acc = __builtin_amdgcn_mfma_f32_16x16x32_bf16(a[1], bw[1][ct], acc, 0, 0, 0);
            #pragma unroll
            for (int r = 0; r < 4; ++r) {
                float v = acc[r] + bias[ct];
                Z2[(rbase + q * 4 + r) * 64 + ct * 16 + col] = f2bf(v);
                sA[ct] += v; qA[ct] += v * v;
            }
        }
    }

    #pragma unroll
    for (int ct = 0; ct < 4; ++ct) {
        float s = sA[ct], qq = qA[ct];
        s  += __shfl_xor(s, 16);  s  += __shfl_xor(s, 32);
        qq += __shfl_xor(qq, 16); qq += __shfl_xor(qq, 32);
        if (q == 0) { redS[w][ct * 16 + col] = s; redQ[w][ct * 16 + col] = qq; }
    }
    __syncthreads();
    if (t < 64) {
        float S = redS[0][t] + redS[1][t] + redS[2][t] + redS[3][t];
        float Q = redQ[0][t] + redQ[1][t] + redQ[2][t] + redQ[3][t];
        atomicAdd(&sum2[t], S);
        atomicAdd(&sq2[t], Q);
    }
}

// ---------------------------------------------------------------------------
// K7: out = relu(z2*scale2+shift2) + x   (float4 elementwise)
// ---------------------------------------------------------------------------
__global__ __launch_bounds__(256) void k_out(
    const float* __restrict__ x, const unsigned short* __restrict__ Z2,
    const float* __restrict__ scale2, const float* __restrict__ shift2,
    float* __restrict__ out)
{
    const int i  = blockIdx.x * 256 + threadIdx.x;
    const int c0 = (i & 15) * 4;
    float4 xv = reinterpret_cast<const float4*>(x)[i];
    ushort4 zv = reinterpret_cast<const ushort4*>(Z2)[i];
    float4 o;
    o.x = fmaxf(fmaf(bf2f(zv.x), scale2[c0 + 0], shift2[c0 + 0]), 0.f) + xv.x;
    o.y = fmaxf(fmaf(bf2f(zv.y), scale2[c0 + 1], shift2[c0 + 1]), 0.f) + xv.y;
    o.z = fmaxf(fmaf(bf2f(zv.z), scale2[c0 + 2], shift2[c0 + 2]), 0.f) + xv.z;
    o.w = fmaxf(fmaf(bf2f(zv.w), scale2[c0 + 3], shift2[c0 + 3]), 0.f) + xv.w;
    reinterpret_cast<float4*>(out)[i] = o;
}

// ---------------------------------------------------------------------------
extern "C" void kernel_launch(void* const* d_in, const int* in_sizes, int n_in,
                              void* d_out, int out_size, void* d_ws, size_t ws_size,
                              hipStream_t stream)
{
    const float* x   = (const float*)d_in[0];
    const float* w11 = (const float*)d_in[1];
    const float* b11 = (const float*)d_in[2];
    const float* w12 = (const float*)d_in[3];
    const float* b12 = (const float*)d_in[4];
    const float* w21 = (const float*)d_in[5];
    const float* b21 = (const float*)d_in[6];
    const float* w22 = (const float*)d_in[7];
    const float* b22 = (const float*)d_in[8];
    const float* uW1 = (const float*)d_in[9];
    const float* ub1 = (const float*)d_in[10];
    const float* g1  = (const float*)d_in[11];
    const float* be1 = (const float*)d_in[12];
    const float* uW2 = (const float*)d_in[13];
    const float* ub2 = (const float*)d_in[14];
    const float* g2  = (const float*)d_in[15];
    const float* be2 = (const float*)d_in[16];

    char* ws = (char*)d_ws;
    const size_t BUF = (size_t)NROWS * 64 * sizeof(unsigned short);  // 128 MiB
    unsigned short* B0 = (unsigned short*)ws;              // M1 -> H -> Z2
    unsigned short* B1 = (unsigned short*)(ws + BUF);      // M2 -> Z1
    float* stats  = (float*)(ws + 2 * BUF);                // 512 floats
    float* sum1   = stats;        float* sq1    = stats + 64;
    float* sum2   = stats + 128;  float* sq2    = stats + 192;
    float* scale1 = stats + 256;  float* shift1 = stats + 320;
    float* scale2 = stats + 384;  float* shift2 = stats + 448;
    unsigned short* wb = (unsigned short*)(ws + 2 * BUF + 2048);
    unsigned short* w11b  = wb;           // 4096
    unsigned short* w12b  = wb + 4096;    // 4096
    unsigned short* w21b  = wb + 8192;    // 4096
    unsigned short* w22b  = wb + 12288;   // 4096
    unsigned short* uW1bt = wb + 16384;   // 8192
    unsigned short* uW2bt = wb + 24576;   // 4096

    hipMemsetAsync(stats, 0, 256 * sizeof(float), stream);

    k_prep<<<1, 256, 0, stream>>>(w11, w12, w21, w22, uW1, uW2,
                                  w11b, w12b, w21b, w22b, uW1bt, uW2bt);
    k_mlp<<<2048, 256, 0, stream>>>(x, w11b, b11, w12b, b12, w21b, b21, w22b, b22, B0, B1);
    k_corr<<<4096, 256, 0, stream>>>(B0, B1);
    k_fc1<<<2048, 256, 0, stream>>>(x, B0, uW1bt, ub1, B1, sum1, sq1);
    k_final<<<1, 64, 0, stream>>>(sum1, sq1, g1, be1, scale1, shift1);
    k_fc2<<<2048, 256, 0, stream>>>(B1, uW2bt, ub2, scale1, shift1, B0, sum2, sq2);
    k_final<<<1, 64, 0, stream>>>(sum2, sq2, g2, be2, scale2, shift2);
    k_out<<<NROWS * 64 / 4 / 256, 256, 0, stream>>>(x, B0, scale2, shift2, (float*)d_out);
}